// Round 1
// baseline (156.663 us; speedup 1.0000x reference)
//
#include <hip/hip_runtime.h>
#include <stdint.h>

#define B_ 4
#define C_ 512
#define N_ 4096
#define D_ 64

typedef __attribute__((ext_vector_type(8))) short short8;
typedef __attribute__((ext_vector_type(4))) float f32x4;
typedef unsigned short ushort_t;

static __device__ __forceinline__ ushort_t f2bf(float f) {
    union { float f; uint32_t u; } v; v.f = f;
    uint32_t u = v.u;
    uint32_t r = u + 0x7FFFu + ((u >> 16) & 1u);
    return (ushort_t)(r >> 16);
}

// -------------------------------------------------------------------------
// Kernel 1: F/G/H projections.
// out[n, o] = sum_c x[b, c, n] * w[o, c] + bias[o]  for w in {wf, wg, wh}
// Stored location-major: Ft/Gt/Ht[b][n][d] (bf16), so attention reads rows.
// Block: 256 thr (4 waves). Tile: 64 locations x 192 outputs. K-chunks of 32.
// MFMA 16x16x32 bf16: A[m=loc, k=c] from LDS As, B[k=c, n=o] from LDS Bs.
// Both fragments use the same k-map kappa(l,b) = 8*(l>>4)+b  (bijection => OK).
// -------------------------------------------------------------------------
__global__ __launch_bounds__(256) void proj_fgh(
    const float* __restrict__ x,
    const float* __restrict__ wf, const float* __restrict__ bf,
    const float* __restrict__ wg, const float* __restrict__ bg,
    const float* __restrict__ wh, const float* __restrict__ bh,
    ushort_t* __restrict__ Ft, ushort_t* __restrict__ Gt, ushort_t* __restrict__ Ht)
{
    const int b    = blockIdx.y;
    const int n0   = blockIdx.x * 64;
    const int tid  = threadIdx.x;
    const int wave = tid >> 6;
    const int lane = tid & 63;
    const int g    = lane >> 4;
    const int r    = lane & 15;

    __shared__ ushort_t As[64][40];   // [loc][k], row stride 40 (80B) to spread banks
    __shared__ ushort_t Bs[192][40];  // [o][k]

    f32x4 acc[12];
    #pragma unroll
    for (int t = 0; t < 12; ++t) acc[t] = (f32x4){0.f, 0.f, 0.f, 0.f};

    for (int k0 = 0; k0 < C_; k0 += 32) {
        // ---- stage A: x[b][k0+k][n0+m] -> As[m][k] (transpose on the fly)
        {
            const int k  = tid >> 3;        // 0..31
            const int mb = (tid & 7) * 8;   // 0..56
            const float* src = x + ((size_t)b * C_ + (k0 + k)) * N_ + n0 + mb;
            float4 v0 = *(const float4*)src;
            float4 v1 = *(const float4*)(src + 4);
            As[mb + 0][k] = f2bf(v0.x);
            As[mb + 1][k] = f2bf(v0.y);
            As[mb + 2][k] = f2bf(v0.z);
            As[mb + 3][k] = f2bf(v0.w);
            As[mb + 4][k] = f2bf(v1.x);
            As[mb + 5][k] = f2bf(v1.y);
            As[mb + 6][k] = f2bf(v1.z);
            As[mb + 7][k] = f2bf(v1.w);
        }
        // ---- stage B: w[o][k0+kb..] -> Bs[o][kb..]
        {
            const int kb = (tid & 7) * 4;   // 0..28
            #pragma unroll
            for (int it = 0; it < 6; ++it) {
                const int o = it * 32 + (tid >> 3);   // 0..191
                const float* wsrc = (o < 64)  ? (wf + (size_t)o * C_)
                                  : (o < 128) ? (wg + (size_t)(o - 64) * C_)
                                              : (wh + (size_t)(o - 128) * C_);
                float4 v = *(const float4*)(wsrc + k0 + kb);
                Bs[o][kb + 0] = f2bf(v.x);
                Bs[o][kb + 1] = f2bf(v.y);
                Bs[o][kb + 2] = f2bf(v.z);
                Bs[o][kb + 3] = f2bf(v.w);
            }
        }
        __syncthreads();
        // ---- MFMA: wave owns m-tile = wave*16 (16 locations), all 12 o-tiles
        short8 a = *(const short8*)&As[wave * 16 + r][8 * g];
        #pragma unroll
        for (int t = 0; t < 12; ++t) {
            short8 bb = *(const short8*)&Bs[t * 16 + r][8 * g];
            acc[t] = __builtin_amdgcn_mfma_f32_16x16x32_bf16(a, bb, acc[t], 0, 0, 0);
        }
        __syncthreads();
    }

    // ---- epilogue: D col = lane&15 (= o within tile), row = 4*(lane>>4)+j (= loc)
    #pragma unroll
    for (int t = 0; t < 12; ++t) {
        const int o  = t * 16 + r;      // 0..191; segment uniform within a given t
        const int oo = o & 63;
        const float* bias = (o < 64) ? bf : (o < 128) ? bg : bh;
        ushort_t*    dst  = (o < 64) ? Ft : (o < 128) ? Gt : Ht;
        const float bbv = bias[oo];
        #pragma unroll
        for (int j = 0; j < 4; ++j) {
            const int loc = n0 + wave * 16 + 4 * g + j;
            dst[((size_t)b * N_ + loc) * D_ + oo] = f2bf(acc[t][j] + bbv);
        }
    }
}

// -------------------------------------------------------------------------
// Kernel 2: flash attention.  Q=Gt, K=Ft, V=Ht, all (N x 64) bf16 row-major.
// O[j,:] = sum_i softmax_i(K_i . Q_j) V_i   -> Ot[b][j][d] bf16
// Block: 256 thr (4 waves); wave w owns 16 queries j0..j0+15. 32-key chunks.
// S-MFMA (swapped): D[m=i, n=j] = A(K-tile)[i,d] * B(Q^T)[d,j]; both frags read
//   row-major rows with kappa = 8*(l>>4)+b over d.
// PV-MFMA: D[m=d, n=j] = A(V^T)[d,i] * B(P)[i,j]; both use split kappa'
//   = 4*(l>>4) + (b&3) + 16*(b>>2), which is EXACTLY the layout the S-MFMA
//   output regs land in -> zero shuffles for P.
// -------------------------------------------------------------------------
__global__ __launch_bounds__(256) void attn(
    const ushort_t* __restrict__ Ft, const ushort_t* __restrict__ Gt,
    const ushort_t* __restrict__ Ht, ushort_t* __restrict__ Ot)
{
    const int b    = blockIdx.y;
    const int wave = threadIdx.x >> 6;
    const int lane = threadIdx.x & 63;
    const int g    = lane >> 4;
    const int r    = lane & 15;
    const int j0   = blockIdx.x * 64 + wave * 16;

    const ushort_t* Qb = Gt + (size_t)b * N_ * D_;
    const ushort_t* Kb = Ft + (size_t)b * N_ * D_;
    const ushort_t* Vb = Ht + (size_t)b * N_ * D_;

    // Q fragments hoisted: lane needs Q[j0 + (l&15)][8g + b (+32)]
    const short8 q0 = *(const short8*)&Qb[(size_t)(j0 + r) * D_ + 8 * g];
    const short8 q1 = *(const short8*)&Qb[(size_t)(j0 + r) * D_ + 32 + 8 * g];

    f32x4 oacc[4];
    #pragma unroll
    for (int t = 0; t < 4; ++t) oacc[t] = (f32x4){0.f, 0.f, 0.f, 0.f};
    float m_run = -1e30f;
    float l_run = 0.f;

    for (int i0 = 0; i0 < N_; i0 += 32) {
        // K fragments (2 i-tiles x 2 d-halves)
        const ushort_t* kp = Kb + (size_t)(i0 + r) * D_ + 8 * g;
        const short8 k00 = *(const short8*)kp;
        const short8 k01 = *(const short8*)(kp + 32);
        const short8 k10 = *(const short8*)(kp + 16 * D_);
        const short8 k11 = *(const short8*)(kp + 16 * D_ + 32);

        f32x4 s0 = (f32x4){0.f, 0.f, 0.f, 0.f};
        f32x4 s1 = (f32x4){0.f, 0.f, 0.f, 0.f};
        s0 = __builtin_amdgcn_mfma_f32_16x16x32_bf16(k00, q0, s0, 0, 0, 0);
        s0 = __builtin_amdgcn_mfma_f32_16x16x32_bf16(k01, q1, s0, 0, 0, 0);
        s1 = __builtin_amdgcn_mfma_f32_16x16x32_bf16(k10, q0, s1, 0, 0, 0);
        s1 = __builtin_amdgcn_mfma_f32_16x16x32_bf16(k11, q1, s1, 0, 0, 0);
        // lane holds S[i, j]: j = r (fixed per lane), i = i0 + 4g + reg (+16 for s1)

        // online softmax over i (rows): in-lane over 8 regs, then lanes ^16, ^32
        float cmax = fmaxf(fmaxf(fmaxf(s0[0], s0[1]), fmaxf(s0[2], s0[3])),
                           fmaxf(fmaxf(s1[0], s1[1]), fmaxf(s1[2], s1[3])));
        cmax = fmaxf(cmax, __shfl_xor(cmax, 16));
        cmax = fmaxf(cmax, __shfl_xor(cmax, 32));
        const float mnew  = fmaxf(m_run, cmax);
        const float scale = __expf(m_run - mnew);

        float p[8];
        float csum = 0.f;
        #pragma unroll
        for (int j = 0; j < 4; ++j) {
            p[j]     = __expf(s0[j] - mnew);
            p[4 + j] = __expf(s1[j] - mnew);
            csum += p[j] + p[4 + j];
        }
        csum += __shfl_xor(csum, 16);
        csum += __shfl_xor(csum, 32);
        l_run = l_run * scale + csum;
        m_run = mnew;

        #pragma unroll
        for (int t = 0; t < 4; ++t) oacc[t] *= scale;

        // P fragment: b 0..3 = s0 regs (i=4g+b), b 4..7 = s1 regs (i=16+4g+b-4)
        short8 pf;
        #pragma unroll
        for (int j = 0; j < 8; ++j) pf[j] = (short)f2bf(p[j]);

        // V^T fragments: a[b] = V[i0 + kappa'(l,b)][16t + r]
        const ushort_t* vbase = Vb + (size_t)(i0 + 4 * g) * D_ + r;
        #pragma unroll
        for (int t = 0; t < 4; ++t) {
            short8 vf;
            #pragma unroll
            for (int q = 0; q < 4; ++q) {
                vf[q]     = (short)vbase[(size_t)q * D_ + t * 16];
                vf[4 + q] = (short)vbase[(size_t)q * D_ + 16 * D_ + t * 16];
            }
            oacc[t] = __builtin_amdgcn_mfma_f32_16x16x32_bf16(vf, pf, oacc[t], 0, 0, 0);
        }
    }

    const float inv_l = 1.0f / l_run;   // l_run is per-j (= per-lane after reduce)
    #pragma unroll
    for (int t = 0; t < 4; ++t) {
        #pragma unroll
        for (int j = 0; j < 4; ++j) {
            const int d = 16 * t + 4 * g + j;
            Ot[((size_t)b * N_ + j0 + r) * D_ + d] = f2bf(oacc[t][j] * inv_l);
        }
    }
}

// -------------------------------------------------------------------------
// Kernel 3: output projection + residual.
// y[b,co,n] = gamma * ( sum_k wv[co,k] * Ot[b,n,k] + bv[co] ) + x[b,co,n]
// Block: 256 thr (4 waves). Tile: 64 co x 64 n. K=64 -> 2 MFMAs per n-subtile.
// A[m=co, k] = wv (fp32 -> bf16 on the fly); B[k, n=loc] = Ot rows. Same kappa.
// -------------------------------------------------------------------------
__global__ __launch_bounds__(256) void outproj(
    const ushort_t* __restrict__ Ot, const float* __restrict__ wv,
    const float* __restrict__ bv, const float* __restrict__ gamma,
    const float* __restrict__ x, float* __restrict__ y)
{
    const int b    = blockIdx.z;
    const int wave = threadIdx.x >> 6;
    const int lane = threadIdx.x & 63;
    const int g    = lane >> 4;
    const int r    = lane & 15;
    const int co0  = blockIdx.y * 64 + wave * 16;
    const int n0   = blockIdx.x * 64;

    // A fragments from wv[co][k] (convert fp32 -> bf16)
    const float* wrow = wv + (size_t)(co0 + r) * D_ + 8 * g;
    short8 a0, a1;
    #pragma unroll
    for (int j = 0; j < 8; ++j) {
        a0[j] = (short)f2bf(wrow[j]);
        a1[j] = (short)f2bf(wrow[32 + j]);
    }

    f32x4 acc[4];
    #pragma unroll
    for (int t = 0; t < 4; ++t) acc[t] = (f32x4){0.f, 0.f, 0.f, 0.f};

    #pragma unroll
    for (int t = 0; t < 4; ++t) {
        const ushort_t* op = Ot + ((size_t)b * N_ + n0 + 16 * t + r) * D_ + 8 * g;
        short8 b0 = *(const short8*)op;
        short8 b1 = *(const short8*)(op + 32);
        acc[t] = __builtin_amdgcn_mfma_f32_16x16x32_bf16(a0, b0, acc[t], 0, 0, 0);
        acc[t] = __builtin_amdgcn_mfma_f32_16x16x32_bf16(a1, b1, acc[t], 0, 0, 0);
    }

    const float gm = *gamma;
    #pragma unroll
    for (int t = 0; t < 4; ++t) {
        #pragma unroll
        for (int j = 0; j < 4; ++j) {
            const int co = co0 + 4 * g + j;
            const int n  = n0 + 16 * t + r;
            const size_t idx = ((size_t)b * C_ + co) * N_ + n;
            y[idx] = gm * (acc[t][j] + bv[co]) + x[idx];
        }
    }
}

// -------------------------------------------------------------------------
extern "C" void kernel_launch(void* const* d_in, const int* in_sizes, int n_in,
                              void* d_out, int out_size, void* d_ws, size_t ws_size,
                              hipStream_t stream) {
    const float* x     = (const float*)d_in[0];
    const float* wf    = (const float*)d_in[1];
    const float* bf    = (const float*)d_in[2];
    const float* wg    = (const float*)d_in[3];
    const float* bg    = (const float*)d_in[4];
    const float* wh    = (const float*)d_in[5];
    const float* bh    = (const float*)d_in[6];
    const float* wv    = (const float*)d_in[7];
    const float* bv    = (const float*)d_in[8];
    const float* gamma = (const float*)d_in[9];
    float* y = (float*)d_out;

    const size_t plane = (size_t)B_ * N_ * D_;   // 1M elements
    ushort_t* Ft = (ushort_t*)d_ws;
    ushort_t* Gt = Ft + plane;
    ushort_t* Ht = Gt + plane;
    ushort_t* Ot = Ht + plane;                   // total 8 MB of d_ws

    proj_fgh<<<dim3(N_ / 64, B_), 256, 0, stream>>>(x, wf, bf, wg, bg, wh, bh, Ft, Gt, Ht);
    attn<<<dim3(N_ / 64, B_), 256, 0, stream>>>(Ft, Gt, Ht, Ot);
    outproj<<<dim3(N_ / 64, C_ / 64, B_), 256, 0, stream>>>(Ot, wv, bv, gamma, x, y);
}